// Round 8
// baseline (152.122 us; speedup 1.0000x reference)
//
#include <hip/hip_runtime.h>
#include <stdint.h>
#include <math.h>

#define T_STEPS 4096
#define BATCH   256
#define NB_BLK  256      // 16-step spike blocks (scan2/3 bitmap granularity)
#define NSEG    1024     // 4-step cert segments per batch
#define NPASS   8        // 32 rows per pass per wave

// LIF step, threshold=1:  v'=alpha*v+xs; s=max(floor(v'),0); v=v'-s
__device__ __forceinline__ float lif_step(float& v, float xs, float alpha) {
    float vp = fmaf(alpha, v, xs);
    float fr = vp - floorf(vp);
    float vn = fminf(vp, fr);
    float s  = vp - vn;
    v = vn;
    return s;
}

__device__ __forceinline__ float ubf(uint32_t w, int k) {
    return (float)((w >> (k * 8)) & 0xffu);
}

// quad-internal sum via DPP (VALU-rate, no LDS): returns sum over the 4
// lanes of the quad, valid in all 4 lanes.  quad_perm[1,0,3,2]=0xB1 (xor1),
// quad_perm[2,3,0,1]=0x4E (xor2).
__device__ __forceinline__ float quad_sum(float v) {
    int j = __builtin_amdgcn_mov_dpp(__float_as_int(v), 0xB1, 0xF, 0xF, true);
    float r = v + __int_as_float(j);
    int k = __builtin_amdgcn_mov_dpp(__float_as_int(r), 0x4E, 0xF, 0xF, true);
    return r + __int_as_float(k);
}

__device__ __forceinline__ float dot16(const float wr[16],
    float4 c0, float4 c1, float4 c2, float4 c3)
{
    float p0 = fmaf(wr[1], c0.y, wr[0] * c0.x);
    p0 = fmaf(wr[2], c0.z, p0);  p0 = fmaf(wr[3], c0.w, p0);
    float p1 = fmaf(wr[5], c1.y, wr[4] * c1.x);
    p1 = fmaf(wr[6], c1.z, p1);  p1 = fmaf(wr[7], c1.w, p1);
    float p2 = fmaf(wr[9], c2.y, wr[8] * c2.x);
    p2 = fmaf(wr[10], c2.z, p2); p2 = fmaf(wr[11], c2.w, p2);
    float p3 = fmaf(wr[13], c3.y, wr[12] * c3.x);
    p3 = fmaf(wr[14], c3.z, p3); p3 = fmaf(wr[15], c3.w, p3);
    return (p0 + p1) + (p2 + p3);
}

// R21: COALESCED ownership.  R20's thread=segment mapping made every x-load
// instruction touch 64 cache lines (lane-private 256B blocks, 8x TA
// transaction inflation) -> 61us kernel with only ~9us VALU + ~6us HBM.
// New mapping: lane = (row, quad-slot): load instr reads xq4[base+ln] --
// perfectly coalesced; the lane's float4 IS channels 4q..4q+3 of one row.
// Dots complete in-quad via DPP quad_perm adds (VALU-rate).  Per 32-row
// wave-private pass: phase1 computes y[row][c] (w premultiplied in LDS,
// broadcast reads) into a 2.5KB padded y-slab; phase2 remaps lanes to
// (segment, channel), runs the exact 4-step recurrence, writes cert
// {end f32, m0 u16 round-up-quantized: ceil encode => decode >= m, 65535
// decodes +huge -> sound, over-flags only}.  All wave-private, zero in-loop
// barriers, x prefetched one pass ahead.  Live VGPRs ~55 < 64: no spill.
// Cert LDS 96KB + y-slabs 40KB + w 1KB + masks ~3KB = ~140KB.
// Composition (16ch x 8 eighths, 40-seg warmup), parallel repair, fused
// flag-gated scan2/scan3 tails: unchanged from R20 except cert accessors.
__global__ __launch_bounds__(1024) void fused(
    const float* __restrict__ x, const float* __restrict__ w1,
    const float* __restrict__ w2, const float* __restrict__ w3,
    float* __restrict__ out, uint8_t* __restrict__ s1t,
    uint8_t* __restrict__ s2t,
    float alpha, float one_m, float alpha4)
{
    const int tid = threadIdx.x;
    const int b   = blockIdx.x;
    const int wv  = tid >> 6;
    const int ln  = tid & 63;

    __shared__ float          endf[NSEG * 16];        // 64 KiB  end, [s*16+c]
    __shared__ unsigned short m0q[NSEG * 16];         // 32 KiB  m0 (u16 q)
    __shared__ __align__(16) float ylds[16 * 640];    // 40 KiB  y slabs
    __shared__ float          wlds[256];              // 1 KiB   one_m*w1
    __shared__ uint32_t sh_badseg[16][NSEG / 32];     // 2 KiB
    __shared__ uint8_t  sh_bm1[NB_BLK];               // 256 B
    __shared__ uint8_t  sh_bm2[NB_BLK];               // 256 B
    __shared__ int      sh_badch, sh_spike, sh_flag2;

    const float* xb = x + (size_t)b * T_STEPS * 16;      // 65536 floats
    const float4* xq4 = (const float4*)xb;               // 16384 float4

    // ---- init: flags, premultiplied weights -------------------------------
    if (tid < 64)        ((uint32_t*)sh_bm1)[tid] = 0u;
    else if (tid < 128)  ((uint32_t*)sh_bm2)[tid - 64] = 0u;
    else if (tid == 128) { sh_badch = 0; sh_spike = 0; sh_flag2 = 0; }
    if (tid < 256) wlds[tid] = one_m * w1[tid];

    // ---- zero out[b] (overlaps weight/x latency) --------------------------
    float4* o4 = (float4*)(out + (size_t)b * T_STEPS * 10);   // 10240 float4
    float4 z4 = make_float4(0.f, 0.f, 0.f, 0.f);
#pragma unroll
    for (int i = 0; i < 10; ++i) o4[i * 1024 + tid] = z4;
    __syncthreads();   // wlds visible

    // ---- main: 8 wave-private passes of 32 rows ---------------------------
    const int q  = ln & 3;            // quad slot = channel group
    const int rl = ln >> 2;           // row-local 0..15 within half-pass
    const int sl2 = ln >> 4;          // phase2 segment-local base 0..3
    const int c2  = ln & 15;          // phase2 channel
    float4* ylds4 = (float4*)(ylds + wv * 640);
    float*  yldsf = ylds + wv * 640;

    float4 x0 = xq4[wv * 1024 + ln];
    float4 x1 = xq4[wv * 1024 + 64 + ln];

    for (int p = 0; p < NPASS; ++p) {
        const int g0 = wv * 1024 + p * 128;
        float4 n0, n1;
        if (p < NPASS - 1) {                       // prefetch next pass
            n0 = xq4[g0 + 128 + ln];
            n1 = xq4[g0 + 192 + ln];
        }
        float4 pk0 = z4, pk1 = z4;
#pragma unroll
        for (int cb = 0; cb < 2; ++cb) {
            float4 w8[8];
#pragma unroll
            for (int i = 0; i < 8; ++i)
                w8[i] = *(const float4*)&wlds[(cb * 8 + i) * 16 + q * 4];
#pragma unroll
            for (int h = 0; h < 2; ++h) {
                float4 xv = h ? x1 : x0;
#pragma unroll
                for (int i = 0; i < 8; ++i) {
                    const int c = cb * 8 + i;
                    float pr = fmaf(w8[i].y, xv.y, w8[i].x * xv.x);
                    pr = fmaf(w8[i].z, xv.z, pr);
                    pr = fmaf(w8[i].w, xv.w, pr);
                    float y = quad_sum(pr);        // y[row][c], all 4 lanes
                    const bool mine = (q == (c >> 2));
                    float4& pk = h ? pk1 : pk0;
                    if ((c & 3) == 0)      pk.x = mine ? y : pk.x;
                    else if ((c & 3) == 1) pk.y = mine ? y : pk.y;
                    else if ((c & 3) == 2) pk.z = mine ? y : pk.z;
                    else                   pk.w = mine ? y : pk.w;
                }
            }
        }
        // y-slab write: row r' = h*16+rl, pitch 5 float4 (bank spread)
        ylds4[rl * 5 + q]        = pk0;
        ylds4[(16 + rl) * 5 + q] = pk1;

        // ---- phase2: (segment, channel) recurrence + cert -----------------
#pragma unroll
        for (int i = 0; i < 2; ++i) {
            const int sl = i * 4 + sl2;            // 0..7
            float e = 0.0f, m = -1e30f;
#pragma unroll
            for (int j = 0; j < 4; ++j) {
                float y = yldsf[(sl * 4 + j) * 20 + c2];
                e = fmaf(alpha, e, y);
                m = fmaxf(m, e);
            }
            const int sg = wv * 64 + p * 8 + sl;
            endf[sg * 16 + c2] = e;
            int qm = (int)ceilf(fmaf(m, 4096.0f, 32768.0f));
            qm = qm < 0 ? 0 : (qm > 65534 ? 65535 : qm);
            m0q[sg * 16 + c2] = (unsigned short)qm;
        }
        x0 = n0; x1 = n1;
    }
    __syncthreads();   // all cert entries visible

    // ---- composition + certification: 16 ch x 8 eighths (128 lanes) -------
    if (tid < 128) {
        const int c  = tid & 15;
        const int e8 = tid >> 4;
        const int s0 = e8 * 128;
        float vs = 0.0f;
        if (e8 > 0) {   // 40-seg warm-up: alpha4^40 = e^-8 = 3.4e-4 carry err
#pragma unroll 8
            for (int s = s0 - 40; s < s0; ++s)
                vs = fmaf(alpha4, vs, endf[s * 16 + c]);
        }
        uint32_t bw = 0;
        int bad = 0;
#pragma unroll 8
        for (int s = s0; s < s0 + 128; ++s) {
            int qm = m0q[s * 16 + c];
            float m0v = (qm == 65535) ? 1e30f
                      : fmaf((float)qm, 0.000244140625f, -8.0f);
            float vsu = fminf(fmaxf(vs + 1e-3f, 0.0f), 1.0f);
            float bound = fmaf(alpha, vsu, m0v);   // m0 + alpha*vsu (sound)
            if (!(bound < 0.999f)) { bw |= 1u << (s & 31); bad = 1; }
            if ((s & 31) == 31) { sh_badseg[c][s >> 5] = bw; bw = 0; }
            vs = fmaf(alpha4, vs, endf[s * 16 + c]);
        }
        if (bad) atomicOr(&sh_badch, 1 << c);
    }
    __syncthreads();

    // ---- parallel exact repair for cert-bad channels (rare) ---------------
    const int badmask = sh_badch;
    if (badmask) {
        uint4* sz = (uint4*)(s1t + (size_t)b * 16 * T_STEPS);
#pragma unroll
        for (int i = 0; i < 4; ++i) sz[i * 1024 + tid] = make_uint4(0u,0u,0u,0u);
        __syncthreads();   // zeroing ordered before repair spike writes

        int m = badmask;
        for (int i = 0; i < wv; ++i) m &= m - 1;
        if (ln == 0 && m) {
            const int c = __ffs(m) - 1;
            float wc[16];
#pragma unroll
            for (int i = 0; i < 16; ++i) wc[i] = w1[c * 16 + i];
            uint8_t* op = s1t + ((size_t)b * 16 + c) * T_STEPS;
            float v = 0.0f;
            int any = 0;
            for (int w32 = 0; w32 < 32; ++w32) {
                uint32_t bwv = sh_badseg[c][w32];
                const int sb = w32 * 32;
                if (bwv == 0u) {
#pragma unroll 8
                    for (int qq = 0; qq < 32; ++qq)
                        v = fmaf(alpha4, v, endf[(sb + qq) * 16 + c]);
                } else {
                    for (int qq = 0; qq < 32; ++qq) {
                        const int s = sb + qq;
                        if (!((bwv >> qq) & 1u)) {
                            v = fmaf(alpha4, v, endf[s * 16 + c]);
                            continue;
                        }
                        const float4* xr2 = xq4 + (size_t)s * 16;
                        uint32_t sw = 0u;
#pragma unroll
                        for (int j = 0; j < 4; ++j) {
                            float y = dot16(wc, xr2[j*4+0], xr2[j*4+1],
                                                 xr2[j*4+2], xr2[j*4+3]);
                            float sp = lif_step(v, one_m * y, alpha);
                            sw |= ((uint32_t)(int)sp) << (j * 8);
                        }
                        if (sw) {
                            *(uint32_t*)(op + s * 4) = sw;
                            sh_bm1[s >> 2] = 1;
                            any = 1;
                        }
                    }
                }
            }
            if (any) sh_spike = 1;
        }
    }
    __syncthreads();   // orders repair writes + sh_spike/sh_bm1 for readers

    // ---- fused layer-2: sparse scan s1t -> s2t (+ sh_bm2) -----------------
    if (sh_spike) {
        if (tid < 32) {
            const int cc2 = tid;
            float wr2[16];
#pragma unroll
            for (int i = 0; i < 16; ++i) wr2[i] = one_m * w2[cc2 * 16 + i];
            const uint8_t* sb1 = s1t + (size_t)b * 16 * T_STEPS;
            uint4* op2 = (uint4*)(s2t + ((size_t)b * 32 + cc2) * T_STEPS);
            const uint4* bmv = (const uint4*)sh_bm1;
            float v = 0.0f;
            for (int sb = 0; sb < 16; ++sb) {
                uint4 bm = bmv[sb];
                if ((bm.x | bm.y | bm.z | bm.w) == 0u) {
                    if (v != 0.0f) {
                        for (int blk = 0; blk < 16 && v != 0.0f; ++blk) {
#pragma unroll
                            for (int j = 0; j < 16; ++j) v *= alpha;
                        }
                    }
                    continue;
                }
                for (int blk = 0; blk < 16; ++blk) {
                    uint32_t d = (blk < 4) ? bm.x : (blk < 8) ? bm.y
                               : (blk < 12) ? bm.z : bm.w;
                    uint32_t byte = (d >> ((blk & 3) * 8)) & 0xffu;
                    if (byte == 0u) {
                        if (v != 0.0f) {
#pragma unroll
                            for (int j = 0; j < 16; ++j) v *= alpha;
                        }
                        continue;
                    }
                    const int tb = sb * 16 + blk;
                    const int t0 = tb * 16;
                    uint4 S[16];
#pragma unroll
                    for (int c = 0; c < 16; ++c)
                        S[c] = *(const uint4*)(sb1 + (size_t)c * T_STEPS + t0);
                    uint32_t w[4] = {0u, 0u, 0u, 0u};
#pragma unroll
                    for (int j = 0; j < 16; ++j) {
                        float xv[16];
#pragma unroll
                        for (int c = 0; c < 16; ++c) {
                            uint32_t dd = (j < 4) ? S[c].x : (j < 8) ? S[c].y
                                        : (j < 12) ? S[c].z : S[c].w;
                            xv[c] = ubf(dd, j & 3);
                        }
                        float p0 = fmaf(wr2[1], xv[1], wr2[0] * xv[0]);
                        p0 = fmaf(wr2[2], xv[2], p0);   p0 = fmaf(wr2[3], xv[3], p0);
                        float p1 = fmaf(wr2[5], xv[5], wr2[4] * xv[4]);
                        p1 = fmaf(wr2[6], xv[6], p1);   p1 = fmaf(wr2[7], xv[7], p1);
                        float p2 = fmaf(wr2[9], xv[9], wr2[8] * xv[8]);
                        p2 = fmaf(wr2[10], xv[10], p2); p2 = fmaf(wr2[11], xv[11], p2);
                        float p3 = fmaf(wr2[13], xv[13], wr2[12] * xv[12]);
                        p3 = fmaf(wr2[14], xv[14], p3); p3 = fmaf(wr2[15], xv[15], p3);
                        float xs = (p0 + p1) + (p2 + p3);
                        float s = lif_step(v, xs, alpha);
                        w[j >> 2] |= ((uint32_t)(int)s) << ((j & 3) * 8);
                    }
                    op2[tb] = make_uint4(w[0], w[1], w[2], w[3]);
                    if (w[0] | w[1] | w[2] | w[3]) { sh_bm2[tb] = 1; sh_flag2 = 1; }
                }
            }
        }
        __syncthreads();   // s2t/sh_bm2/sh_flag2 visible

        // ---- fused layer-3: sparse scan s2t -> out (pre-zeroed) -----------
        if (sh_flag2 && tid < 16) {
            const int c3 = tid;
            const bool active = (c3 < 10);
            float wr3[32];
#pragma unroll
            for (int i = 0; i < 32; ++i)
                wr3[i] = active ? (one_m * w3[c3 * 32 + i]) : 0.0f;
            const uint8_t* sb2 = s2t + (size_t)b * 32 * T_STEPS;
            const uint4* bmv2 = (const uint4*)sh_bm2;
            float* ob = out + (size_t)b * T_STEPS * 10 + c3;
            float v = 0.0f;
            for (int sb = 0; sb < 16; ++sb) {
                uint4 bm = bmv2[sb];
                if ((bm.x | bm.y | bm.z | bm.w) == 0u) {
                    if (v != 0.0f) {
                        for (int blk = 0; blk < 16 && v != 0.0f; ++blk) {
#pragma unroll
                            for (int j = 0; j < 16; ++j) v *= alpha;
                        }
                    }
                    continue;
                }
                for (int blk = 0; blk < 16; ++blk) {
                    uint32_t d = (blk < 4) ? bm.x : (blk < 8) ? bm.y
                               : (blk < 12) ? bm.z : bm.w;
                    uint32_t byte = (d >> ((blk & 3) * 8)) & 0xffu;
                    if (byte == 0u) {
                        if (v != 0.0f) {
#pragma unroll
                            for (int j = 0; j < 16; ++j) v *= alpha;
                        }
                        continue;
                    }
                    const int t0 = (sb * 16 + blk) * 16;
                    uint4 S[32];
#pragma unroll
                    for (int c = 0; c < 32; ++c)
                        S[c] = *(const uint4*)(sb2 + (size_t)c * T_STEPS + t0);
#pragma unroll
                    for (int j = 0; j < 16; ++j) {
                        float xv[32];
#pragma unroll
                        for (int c = 0; c < 32; ++c) {
                            uint32_t dd = (j < 4) ? S[c].x : (j < 8) ? S[c].y
                                        : (j < 12) ? S[c].z : S[c].w;
                            xv[c] = ubf(dd, j & 3);
                        }
                        float p0 = fmaf(wr3[1], xv[1], wr3[0] * xv[0]);
                        p0 = fmaf(wr3[2],  xv[2],  p0); p0 = fmaf(wr3[3],  xv[3],  p0);
                        p0 = fmaf(wr3[4],  xv[4],  p0); p0 = fmaf(wr3[5],  xv[5],  p0);
                        p0 = fmaf(wr3[6],  xv[6],  p0); p0 = fmaf(wr3[7],  xv[7],  p0);
                        float p1 = fmaf(wr3[9], xv[9], wr3[8] * xv[8]);
                        p1 = fmaf(wr3[10], xv[10], p1); p1 = fmaf(wr3[11], xv[11], p1);
                        p1 = fmaf(wr3[12], xv[12], p1); p1 = fmaf(wr3[13], xv[13], p1);
                        p1 = fmaf(wr3[14], xv[14], p1); p1 = fmaf(wr3[15], xv[15], p1);
                        float p2 = fmaf(wr3[17], xv[17], wr3[16] * xv[16]);
                        p2 = fmaf(wr3[18], xv[18], p2); p2 = fmaf(wr3[19], xv[19], p2);
                        p2 = fmaf(wr3[20], xv[20], p2); p2 = fmaf(wr3[21], xv[21], p2);
                        p2 = fmaf(wr3[22], xv[22], p2); p2 = fmaf(wr3[23], xv[23], p2);
                        float p3 = fmaf(wr3[25], xv[25], wr3[24] * xv[24]);
                        p3 = fmaf(wr3[26], xv[26], p3); p3 = fmaf(wr3[27], xv[27], p3);
                        p3 = fmaf(wr3[28], xv[28], p3); p3 = fmaf(wr3[29], xv[29], p3);
                        p3 = fmaf(wr3[30], xv[30], p3); p3 = fmaf(wr3[31], xv[31], p3);
                        float xs = (p0 + p1) + (p2 + p3);
                        float s = lif_step(v, xs, alpha);
                        if (active && s != 0.0f) ob[(size_t)(t0 + j) * 10] = s;
                    }
                }
            }
        }
    }
}

extern "C" void kernel_launch(void* const* d_in, const int* in_sizes, int n_in,
                              void* d_out, int out_size, void* d_ws, size_t ws_size,
                              hipStream_t stream)
{
    const float* data = (const float*)d_in[0];
    const float* w1   = (const float*)d_in[1];
    const float* w2   = (const float*)d_in[2];
    const float* w3   = (const float*)d_in[3];
    float* out = (float*)d_out;

    // ws layout (48 MiB):
    //   [0, 16M)    s1t  u8 [256][16][4096]  (dense-zeroed only for bad b)
    //   [16M, 48M)  s2t  u8 [256][32][4096]  (sparse: only bm2-set blocks valid)
    uint8_t* ws  = (uint8_t*)d_ws;
    uint8_t* s1t = ws;
    uint8_t* s2t = ws + (16u << 20);

    const float alpha  = expf(-1.0f / 20.0f);
    const float one_m  = 1.0f - alpha;
    const float alpha4 = expf(-4.0f / 20.0f);

    fused<<<BATCH, 1024, 0, stream>>>(data, w1, w2, w3, out, s1t, s2t,
                                      alpha, one_m, alpha4);
}